// Round 1
// baseline (275.628 us; speedup 1.0000x reference)
//
#include <hip/hip_runtime.h>

// Problem constants (from reference)
#define C_IN  128
#define C_RES 64
#define D     512
#define DD    (D * D)          // 262144

// ---------------------------------------------------------------------------
// Kernel A: S[o, i] = sum_c W[c, o, i]
// Thread per (o, i4) where i4 indexes float4 chunks of the i dimension.
// Coalesced: lanes cover consecutive i4 -> 16 B/lane contiguous per c-step.
// ---------------------------------------------------------------------------
__global__ void sum_c_kernel(const float* __restrict__ W,
                             float* __restrict__ S, int C) {
    int t = blockIdx.x * blockDim.x + threadIdx.x;   // 0 .. 512*128-1
    // o = t / 128, i4 = t % 128
    const float4* Wp = (const float4*)W + (size_t)t; // == o*(D/4) + i4 within one c-slice
    float4 acc = make_float4(0.f, 0.f, 0.f, 0.f);
#pragma unroll 16
    for (int c = 0; c < C; ++c) {
        float4 w = Wp[(size_t)c * (DD / 4)];
        acc.x += w.x; acc.y += w.y; acc.z += w.z; acc.w += w.w;
    }
    ((float4*)S)[t] = acc;
}

// ---------------------------------------------------------------------------
// Kernel B: node[i] = argmax_o S[o, i]   (first index wins on ties)
// One wave (64 threads) per column i.
// ---------------------------------------------------------------------------
__global__ void argmax_kernel(const float* __restrict__ S,
                              int* __restrict__ node) {
    int i = blockIdx.x;
    int lane = threadIdx.x;           // 0..63
    float best = -__builtin_inff();
    int bidx = 0x7fffffff;
    for (int o = lane; o < D; o += 64) {
        float v = S[o * D + i];
        if (v > best) { best = v; bidx = o; }   // ascending o: strict > keeps first
    }
    for (int off = 32; off > 0; off >>= 1) {
        float ov = __shfl_down(best, off);
        int   oi = __shfl_down(bidx, off);
        if (ov > best || (ov == best && oi < bidx)) { best = ov; bidx = oi; }
    }
    if (lane == 0) node[i] = bidx;
}

// ---------------------------------------------------------------------------
// Kernel C: diff[c, node[i]] += (relu?) x[c, i] * W[c, node[i], i]
// Thread per (c, i). diff must be pre-zeroed.
// ---------------------------------------------------------------------------
__global__ void scatter_kernel(const float* __restrict__ W,
                               const float* __restrict__ xin,
                               const int* __restrict__ node,
                               float* __restrict__ diff,
                               int relu_input) {
    int t = blockIdx.x * blockDim.x + threadIdx.x;   // c*D + i
    int c = t >> 9;
    int i = t & (D - 1);
    int n = node[i];
    float xv = xin[t];
    if (relu_input) xv = fmaxf(xv, 0.f);
    float w = W[(size_t)c * DD + (size_t)n * D + i];
    atomicAdd(&diff[c * D + n], w * xv);
}

// ---------------------------------------------------------------------------
// Kernel D: stage-1 1x1 conv: x2[o, d] = relu( bc[o] + sum_c Wc[o,c]*diff[c,d] )
// One block per o, 512 threads over d. diff is L2-resident (256 KB).
// ---------------------------------------------------------------------------
__global__ void conv_relu_kernel(const float* __restrict__ Wc,
                                 const float* __restrict__ bc,
                                 const float* __restrict__ diff,
                                 float* __restrict__ out, int C) {
    int o = blockIdx.x;
    int d = threadIdx.x;
    float acc = bc[o];
#pragma unroll 8
    for (int c = 0; c < C; ++c)
        acc += Wc[o * C + c] * diff[c * D + d];
    out[o * D + d] = fmaxf(acc, 0.f);
}

// ---------------------------------------------------------------------------
// Kernel E: final: out[o, d] = relu(x[o,d]) + bc2[o] + sum_c Wc2[o,c]*diff2[c,d]
// ---------------------------------------------------------------------------
__global__ void final_kernel(const float* __restrict__ Wc2,
                             const float* __restrict__ bc2,
                             const float* __restrict__ diff2,
                             const float* __restrict__ x,
                             float* __restrict__ out) {
    int o = blockIdx.x;            // 0..127
    int d = threadIdx.x;           // 0..511
    float acc = bc2[o];
#pragma unroll 8
    for (int c = 0; c < C_RES; ++c)
        acc += Wc2[o * C_RES + c] * diff2[c * D + d];
    out[o * D + d] = acc + fmaxf(x[o * D + d], 0.f);
}

extern "C" void kernel_launch(void* const* d_in, const int* in_sizes, int n_in,
                              void* d_out, int out_size, void* d_ws, size_t ws_size,
                              hipStream_t stream) {
    const float* x   = (const float*)d_in[0];   // (1, 128, 512)
    const float* W1  = (const float*)d_in[1];   // (128, 512, 512)
    const float* Wc1 = (const float*)d_in[2];   // (64, 128)
    const float* bc1 = (const float*)d_in[3];   // (64,)
    const float* W2  = (const float*)d_in[4];   // (64, 512, 512)
    const float* Wc2 = (const float*)d_in[5];   // (128, 64)
    const float* bc2 = (const float*)d_in[6];   // (128,)
    float* out = (float*)d_out;                 // (1, 128, 512) fp32

    // Workspace carve-up (floats)
    float* ws    = (float*)d_ws;
    float* S1    = ws;                  // 262144
    float* S2    = S1 + DD;             // 262144
    float* diff1 = S2 + DD;             // 128*512 = 65536
    float* x2    = diff1 + C_IN * D;    // 64*512  = 32768
    float* diff2 = x2 + C_RES * D;      // 64*512  = 32768
    int*   node1 = (int*)(diff2 + C_RES * D);   // 512
    int*   node2 = node1 + D;                   // 512

    // Zero the scatter accumulators (ws is poisoned 0xAA before every call)
    hipMemsetAsync(diff1, 0, (size_t)(C_IN * D) * sizeof(float), stream);
    hipMemsetAsync(diff2, 0, (size_t)(C_RES * D) * sizeof(float), stream);

    // Stage-independent: column sums of W1, W2 (the HBM-dominant work)
    {
        int total = D * (D / 4);        // 65536 threads, one per (o, i4)
        sum_c_kernel<<<total / 256, 256, 0, stream>>>(W1, S1, C_IN);
        sum_c_kernel<<<total / 256, 256, 0, stream>>>(W2, S2, C_RES);
    }
    argmax_kernel<<<D, 64, 0, stream>>>(S1, node1);
    argmax_kernel<<<D, 64, 0, stream>>>(S2, node2);

    // Stage 1: scatter with relu(x), then 1x1 conv + bias + relu -> x2
    scatter_kernel<<<(C_IN * D) / 256, 256, 0, stream>>>(W1, x, node1, diff1, 1);
    conv_relu_kernel<<<C_RES, D, 0, stream>>>(Wc1, bc1, diff1, x2, C_IN);

    // Stage 2: scatter with x2 (already relu'd), then final conv + residual
    scatter_kernel<<<(C_RES * D) / 256, 256, 0, stream>>>(W2, x2, node2, diff2, 0);
    final_kernel<<<C_IN, D, 0, stream>>>(Wc2, bc2, diff2, x, out);
}

// Round 2
// 256.953 us; speedup vs baseline: 1.0727x; 1.0727x over previous
//
#include <hip/hip_runtime.h>

#define C_IN  128
#define C_RES 64
#define D     512
#define DD    (D * D)          // 262144

// ---------------------------------------------------------------------------
// K1: S1[o,i] = sum_c W1[c,o,i]; S2 likewise; also zero diff1|diff2 (98304 f).
// Thread t < DD/4 handles W1 float4-chunk t; t >= DD/4 handles W2 chunk.
// Grid = 384 blocks x 256 = 98304 threads exactly.
// ---------------------------------------------------------------------------
template <int C>
__device__ inline float4 colsum(const float4* __restrict__ Wp) {
    float4 acc = make_float4(0.f, 0.f, 0.f, 0.f);
#pragma unroll 16
    for (int c = 0; c < C; ++c) {
        float4 w = Wp[(size_t)c * (DD / 4)];
        acc.x += w.x; acc.y += w.y; acc.z += w.z; acc.w += w.w;
    }
    return acc;
}

__global__ void sum_zero_kernel(const float* __restrict__ W1,
                                const float* __restrict__ W2,
                                float* __restrict__ S1,
                                float* __restrict__ S2,
                                float* __restrict__ diff_zero) {
    int t = blockIdx.x * 256 + threadIdx.x;       // 0 .. 98303
    if (t < DD / 4) {
        ((float4*)S1)[t] = colsum<C_IN>((const float4*)W1 + t);
    } else {
        int t2 = t - DD / 4;                      // 0 .. 32767
        ((float4*)S2)[t2] = colsum<C_RES>((const float4*)W2 + t2);
    }
    diff_zero[t] = 0.f;                           // diff1 (65536) + diff2 (32768)
}

// ---------------------------------------------------------------------------
// K2: 64 blocks x 256. Blocks 0..31: stage-1 columns [b*16, b*16+16):
//   argmax_o S1[o,i] in-block, then scatter diff1[c,n_i] += W1[c,n_i,i]*relu(x[c,i]).
// Blocks 32..63: stage-2 columns: argmax_o S2 -> node2[i] (global) and
//   pre-gather w2v[c,i] = W2[c,n_i,i].
// Tie-break = first (smallest o), matching jnp/np.argmax.
// ---------------------------------------------------------------------------
__global__ void argmax_scatter_kernel(const float* __restrict__ S1,
                                      const float* __restrict__ S2,
                                      const float* __restrict__ W1,
                                      const float* __restrict__ W2,
                                      const float* __restrict__ x,
                                      float* __restrict__ diff1,
                                      float* __restrict__ w2v,
                                      int* __restrict__ node2) {
    __shared__ float lv[256];
    __shared__ int   li[256];
    __shared__ int   node_s[16];

    const int  tid = threadIdx.x;
    const bool st1 = blockIdx.x < 32;
    const int  i0  = (blockIdx.x & 31) * 16;
    const float* __restrict__ S = st1 ? S1 : S2;

    // Phase A: argmax over o for 16 columns. tid -> (il = tid%16, ol = tid/16).
    const int il = tid & 15;
    const int ol = tid >> 4;                       // 0..15
    float best = -__builtin_inff();
    int   bidx = D;                                // larger than any valid o
#pragma unroll 4
    for (int k = 0; k < 32; ++k) {
        int o = ol + (k << 4);                     // ascending per thread
        float v = S[o * D + i0 + il];              // 16 lanes = 64B contiguous
        if (v > best) { best = v; bidx = o; }      // strict >: first wins
    }
    lv[tid] = best; li[tid] = bidx;
    __syncthreads();
    for (int s = 128; s >= 16; s >>= 1) {
        if (tid < s) {
            float v2 = lv[tid + s]; int i2 = li[tid + s];
            if (v2 > lv[tid] || (v2 == lv[tid] && i2 < li[tid])) {
                lv[tid] = v2; li[tid] = i2;
            }
        }
        __syncthreads();
    }
    if (tid < 16) {
        node_s[tid] = li[tid];
        if (!st1) node2[i0 + tid] = li[tid];
    }
    __syncthreads();

    // Phase B
    if (st1) {
        // 128 c x 16 i = 2048 ops, 8 rounds
        for (int idx = tid; idx < C_IN * 16; idx += 256) {
            int ii = idx & 15;
            int c  = idx >> 4;
            int i  = i0 + ii;
            int n  = node_s[ii];
            float xv = fmaxf(x[c * D + i], 0.f);
            float w  = W1[(size_t)c * DD + (size_t)n * D + i];
            atomicAdd(&diff1[c * D + n], w * xv);
        }
    } else {
        // 64 c x 16 i = 1024 ops, 4 rounds
        for (int idx = tid; idx < C_RES * 16; idx += 256) {
            int ii = idx & 15;
            int c  = idx >> 4;
            int i  = i0 + ii;
            int n  = node_s[ii];
            w2v[c * D + i] = W2[(size_t)c * DD + (size_t)n * D + i];
        }
    }
}

// ---------------------------------------------------------------------------
// K3: fused stage-1 conv (+bias, relu) and stage-2 scatter:
//   x2 = relu(bc1[c] + sum_cc Wc1[c,cc]*diff1[cc,i])
//   diff2[c, node2[i]] += w2v[c,i] * x2
// 128 blocks x 256; c = blockIdx>>1 uniform per block, i = (blockIdx&1)*256+tid.
// ---------------------------------------------------------------------------
__global__ void conv1_scatter2_kernel(const float* __restrict__ Wc1,
                                      const float* __restrict__ bc1,
                                      const float* __restrict__ diff1,
                                      const float* __restrict__ w2v,
                                      const int* __restrict__ node2,
                                      float* __restrict__ diff2) {
    __shared__ float wc[C_IN];
    const int c = blockIdx.x >> 1;                 // 0..63
    const int i = ((blockIdx.x & 1) << 8) + threadIdx.x;
    if (threadIdx.x < C_IN) wc[threadIdx.x] = Wc1[c * C_IN + threadIdx.x];
    __syncthreads();

    float acc = bc1[c];
#pragma unroll 8
    for (int cc = 0; cc < C_IN; ++cc)
        acc += wc[cc] * diff1[cc * D + i];         // lanes = consecutive i
    float x2 = fmaxf(acc, 0.f);
    int n = node2[i];
    atomicAdd(&diff2[c * D + n], w2v[c * D + i] * x2);
}

// ---------------------------------------------------------------------------
// K4: out[o,d] = relu(x[o,d]) + bc2[o] + sum_c Wc2[o,c]*diff2[c,d]
// 256 blocks x 256; o = blockIdx>>1, d = (blockIdx&1)*256+tid.
// ---------------------------------------------------------------------------
__global__ void final_kernel(const float* __restrict__ Wc2,
                             const float* __restrict__ bc2,
                             const float* __restrict__ diff2,
                             const float* __restrict__ x,
                             float* __restrict__ out) {
    __shared__ float wc[C_RES];
    const int o = blockIdx.x >> 1;                 // 0..127
    const int d = ((blockIdx.x & 1) << 8) + threadIdx.x;
    if (threadIdx.x < C_RES) wc[threadIdx.x] = Wc2[o * C_RES + threadIdx.x];
    __syncthreads();

    float acc = bc2[o];
#pragma unroll 8
    for (int c = 0; c < C_RES; ++c)
        acc += wc[c] * diff2[c * D + d];
    out[o * D + d] = acc + fmaxf(x[o * D + d], 0.f);
}

extern "C" void kernel_launch(void* const* d_in, const int* in_sizes, int n_in,
                              void* d_out, int out_size, void* d_ws, size_t ws_size,
                              hipStream_t stream) {
    const float* x   = (const float*)d_in[0];   // (1, 128, 512)
    const float* W1  = (const float*)d_in[1];   // (128, 512, 512)
    const float* Wc1 = (const float*)d_in[2];   // (64, 128)
    const float* bc1 = (const float*)d_in[3];   // (64,)
    const float* W2  = (const float*)d_in[4];   // (64, 512, 512)
    const float* Wc2 = (const float*)d_in[5];   // (128, 64)
    const float* bc2 = (const float*)d_in[6];   // (128,)
    float* out = (float*)d_out;                 // (1, 128, 512) fp32

    // Workspace carve-up (floats); diff1|diff2 contiguous for K1's zeroing.
    float* ws    = (float*)d_ws;
    float* S1    = ws;                          // 262144
    float* S2    = S1 + DD;                     // 262144
    float* diff1 = S2 + DD;                     // 65536
    float* diff2 = diff1 + C_IN * D;            // 32768  (contiguous after diff1)
    float* w2v   = diff2 + C_RES * D;           // 32768
    int*   node2 = (int*)(w2v + C_RES * D);     // 512

    // K1: stream W1+W2 (201 MB, the HBM floor) + zero diff1/diff2
    sum_zero_kernel<<<384, 256, 0, stream>>>(W1, W2, S1, S2, diff1);
    // K2: argmax both stages + stage-1 scatter + stage-2 W-gather
    argmax_scatter_kernel<<<64, 256, 0, stream>>>(S1, S2, W1, W2, x,
                                                  diff1, w2v, node2);
    // K3: stage-1 1x1 conv (+bias,relu) fused with stage-2 scatter
    conv1_scatter2_kernel<<<128, 256, 0, stream>>>(Wc1, bc1, diff1, w2v,
                                                   node2, diff2);
    // K4: stage-2 1x1 conv + bias + residual relu(x)
    final_kernel<<<256, 256, 0, stream>>>(Wc2, bc2, diff2, x, out);
}